// Round 1
// baseline (321.241 us; speedup 1.0000x reference)
//
#include <hip/hip_runtime.h>
#include <math.h>

#define HW    25600   // H*W
#define WID   160
#define HEI   160
#define BB    4
#define CIN   64
#define COUT  64
#define KK    9
#define NBN   102400  // B*H*W (per-channel BN count)

// ---------------------------------------------------------------------------
// K0: transpose w_def (o,c,k) -> wt[k][c][o] for coalesced LDS staging in K4
// ---------------------------------------------------------------------------
__global__ void k0_transpose(const float* __restrict__ w_def, float* __restrict__ wt) {
    int idx = blockIdx.x * 256 + threadIdx.x;   // 0 .. 36863
    if (idx >= COUT * CIN * KK) return;
    int k   = idx / (CIN * COUT);
    int rem = idx % (CIN * COUT);
    int c   = rem / COUT;
    int o   = rem % COUT;
    wt[idx] = w_def[(o * CIN + c) * KK + k];
}

// ---------------------------------------------------------------------------
// K1: offset conv, ODD channels only (even channels are zeroed by
// _convert_offsets and never used). off_odd[b][j][p] , j=0..8 -> channel 2j+1
// ---------------------------------------------------------------------------
__global__ __launch_bounds__(256) void k1_offconv(
        const float* __restrict__ x, const float* __restrict__ w_off,
        const float* __restrict__ b_off, float* __restrict__ off_odd) {
    int tid = blockIdx.x * 256 + threadIdx.x;   // 0 .. 102399
    if (tid >= BB * HW) return;
    int b = tid / HW;
    int p = tid % HW;
    int h = p / WID;

    float acc[9];
#pragma unroll
    for (int j = 0; j < 9; ++j) acc[j] = b_off[2 * j + 1];

    const float* xb = x + b * CIN * HW;
    for (int c = 0; c < CIN; ++c) {
        const float* xc = xb + c * HW;
#pragma unroll
        for (int k = 0; k < 9; ++k) {
            int py = h + k - 4;
            float xv = (py >= 0 && py < HEI) ? xc[p + (k - 4) * WID] : 0.0f;
#pragma unroll
            for (int j = 0; j < 9; ++j) {
                acc[j] = fmaf(w_off[((2 * j + 1) * CIN + c) * KK + k], xv, acc[j]);
            }
        }
    }
#pragma unroll
    for (int j = 0; j < 9; ++j)
        off_odd[(b * 9 + j) * HW + p] = acc[j];
}

// ---------------------------------------------------------------------------
// K2: BN statistics (sum, sumsq) per odd channel. stats[j] = sum, stats[9+j]=sumsq
// grid (9, 16): channel j, chunk of 6400 of the 102400 per-channel elements
// ---------------------------------------------------------------------------
__global__ __launch_bounds__(256) void k2_stats(
        const float* __restrict__ off_odd, float* __restrict__ stats) {
    int j     = blockIdx.x;
    int chunk = blockIdx.y;
    int t     = threadIdx.x;

    float s = 0.f, s2 = 0.f;
    int base = chunk * 6400;
    for (int i = base + t; i < base + 6400; i += 256) {
        int b = i / HW;
        int p = i % HW;
        float v = off_odd[(b * 9 + j) * HW + p];
        s += v; s2 += v * v;
    }
#pragma unroll
    for (int off = 32; off > 0; off >>= 1) {
        s  += __shfl_down(s,  off);
        s2 += __shfl_down(s2, off);
    }
    __shared__ float ls[4], ls2[4];
    int lane = t & 63, wv = t >> 6;
    if (lane == 0) { ls[wv] = s; ls2[wv] = s2; }
    __syncthreads();
    if (t == 0) {
        atomicAdd(&stats[j],     ls[0] + ls[1] + ls[2] + ls[3]);
        atomicAdd(&stats[9 + j], ls2[0] + ls2[1] + ls2[2] + ls2[3]);
    }
}

// ---------------------------------------------------------------------------
// K3: normalize + tanh + _convert_offsets (prefix/suffix sums around k=4).
// In-place on off_odd: each thread owns one pixel's 9 channel values.
// ---------------------------------------------------------------------------
__global__ __launch_bounds__(256) void k3_norm(
        float* __restrict__ off_odd, const float* __restrict__ stats,
        const float* __restrict__ gamma, const float* __restrict__ beta) {
    int tid = blockIdx.x * 256 + threadIdx.x;
    if (tid >= BB * HW) return;
    int b = tid / HW, p = tid % HW;

    float t[9];
#pragma unroll
    for (int j = 0; j < 9; ++j) {
        float mean = stats[j] * (1.0f / NBN);
        float var  = stats[9 + j] * (1.0f / NBN) - mean * mean;
        float inv  = rsqrtf(var + 1e-5f);
        float v = off_odd[(b * 9 + j) * HW + p];
        t[j] = tanhf((v - mean) * inv * gamma[2 * j + 1] + beta[2 * j + 1]);
    }
    float dx[9];
    dx[4] = t[4];
#pragma unroll
    for (int i = 5; i < 9; ++i) dx[i] = dx[i - 1] + t[i];
#pragma unroll
    for (int i = 3; i >= 0; --i) dx[i] = dx[i + 1] + t[i];
#pragma unroll
    for (int j = 0; j < 9; ++j)
        off_odd[(b * 9 + j) * HW + p] = dx[j];
}

// ---------------------------------------------------------------------------
// K4: deformable conv. dy==0 exactly -> py = h-4+k integer, fy=0:
//   s[b,c,k,p] = (1-fx)*x[b,c,py,x0] + fx*x[b,c,py,x0+1]  (masked)
//   out[b,o,p] = sum_{c,k} wt[k][c][o] * s + b_def[o]
// Block: 64 pixels x 64 outputs; LDS S[c][p], W[c][o]; 4x4 micro-tile/thread.
// ---------------------------------------------------------------------------
__global__ __launch_bounds__(256) void k4_deform(
        const float* __restrict__ x, const float* __restrict__ dxn,
        const float* __restrict__ wt, const float* __restrict__ b_def,
        float* __restrict__ out) {
    __shared__ float s_s[64 * 64];   // samples [c][p_local]
    __shared__ float s_w[64 * 64];   // weights [c][o]

    int t   = threadIdx.x;
    int blk = blockIdx.x;            // 0 .. 1599
    int b   = blk / 400;
    int p0  = (blk % 400) * 64;

    int pl = t & 63;                 // staging pixel lane
    int p  = p0 + pl;
    int h  = p / WID, w = p % WID;

    int tp = t & 15;                 // micro-tile pixel group (4 px)
    int to = t >> 4;                 // micro-tile output group (4 o)

    float acc[4][4];
#pragma unroll
    for (int i = 0; i < 4; ++i)
#pragma unroll
        for (int jj = 0; jj < 4; ++jj) acc[i][jj] = 0.f;

    for (int k = 0; k < 9; ++k) {
        // per-pixel sampling params (same for all c; thread owns pixel pl)
        float dx  = dxn[(b * 9 + k) * HW + p];
        int   py  = h + k - 4;
        bool  rowok = (py >= 0) && (py < HEI);
        float px  = (float)w + dx;
        float x0f = floorf(px);
        float fx  = px - x0f;
        int   x0  = (int)x0f;
        bool  v0ok = rowok && (x0 >= 0) && (x0 < WID);
        bool  v1ok = rowok && (x0 + 1 >= 0) && (x0 + 1 < WID);
        int   xi0 = min(max(x0, 0), WID - 1);
        int   xi1 = min(max(x0 + 1, 0), WID - 1);
        int   rowbase = py * WID;    // may be out of range; loads are predicated

        __syncthreads();             // protect LDS from previous iteration's readers
        // stage samples: wave wv stages channels c = wv + 4*iter
#pragma unroll
        for (int iter = 0; iter < 16; ++iter) {
            int c = (t >> 6) + iter * 4;
            const float* xr = x + (b * CIN + c) * HW + rowbase;
            float v0 = v0ok ? xr[xi0] : 0.f;
            float v1 = v1ok ? xr[xi1] : 0.f;
            s_s[c * 64 + pl] = (1.f - fx) * v0 + fx * v1;
        }
        // stage weights (coalesced from pre-transposed wt)
#pragma unroll
        for (int iter = 0; iter < 16; ++iter) {
            int idx = t + iter * 256;
            s_w[idx] = wt[k * 4096 + idx];
        }
        __syncthreads();

        for (int c = 0; c < 64; ++c) {
            float wv[4], sv[4];
            *(float4*)wv = *(const float4*)&s_w[c * 64 + (to << 2)];
            *(float4*)sv = *(const float4*)&s_s[c * 64 + (tp << 2)];
#pragma unroll
            for (int i = 0; i < 4; ++i)
#pragma unroll
                for (int jj = 0; jj < 4; ++jj)
                    acc[i][jj] = fmaf(wv[i], sv[jj], acc[i][jj]);
        }
    }

    // epilogue: add bias, store 4 contiguous pixels per output channel
#pragma unroll
    for (int i = 0; i < 4; ++i) {
        int o = (to << 2) + i;
        float bd = b_def[o];
        float4 r;
        r.x = acc[i][0] + bd;
        r.y = acc[i][1] + bd;
        r.z = acc[i][2] + bd;
        r.w = acc[i][3] + bd;
        *(float4*)&out[(b * COUT + o) * HW + p0 + (tp << 2)] = r;
    }
}

// ---------------------------------------------------------------------------
extern "C" void kernel_launch(void* const* d_in, const int* in_sizes, int n_in,
                              void* d_out, int out_size, void* d_ws, size_t ws_size,
                              hipStream_t stream) {
    const float* x     = (const float*)d_in[0];
    const float* w_off = (const float*)d_in[1];
    const float* b_off = (const float*)d_in[2];
    const float* gamma = (const float*)d_in[3];
    const float* beta  = (const float*)d_in[4];
    const float* w_def = (const float*)d_in[5];
    const float* b_def = (const float*)d_in[6];
    float* out = (float*)d_out;

    float* off_odd = (float*)d_ws;            // 921600 floats (reused in-place as dx)
    float* stats   = off_odd + 921600;        // 18 floats
    float* wt      = stats + 32;              // 36864 floats (aligned)

    k0_transpose<<<144, 256, 0, stream>>>(w_def, wt);
    k1_offconv<<<400, 256, 0, stream>>>(x, w_off, b_off, off_odd);
    hipMemsetAsync(stats, 0, 18 * sizeof(float), stream);
    k2_stats<<<dim3(9, 16), 256, 0, stream>>>(off_odd, stats);
    k3_norm<<<400, 256, 0, stream>>>(off_odd, stats, gamma, beta);
    k4_deform<<<1600, 256, 0, stream>>>(x, off_odd, wt, b_def, out);
}

// Round 2
// 221.015 us; speedup vs baseline: 1.4535x; 1.4535x over previous
//
#include <hip/hip_runtime.h>
#include <math.h>

#define HW    25600
#define WID   160
#define HEI   160
#define BB    4
#define CIN   64
#define COUT  64
#define NBN   102400
#define SROW  66      // LDS row stride (bf16 units): 64 c + 2 pad -> conflict-free

typedef short  bf16x8 __attribute__((ext_vector_type(8)));
typedef float  f32x4  __attribute__((ext_vector_type(4)));

union U4 { int i[4]; bf16x8 v; };

__device__ __forceinline__ unsigned f2bf_rne(float f) {
    union { float f; unsigned u; } v; v.f = f;
    return (v.u + 0x7fffu + ((v.u >> 16) & 1u)) >> 16;
}

// ---------------------------------------------------------------------------
// P0: prep. blocks 0..639: transpose x[b][c][h][w] fp32 -> xbT[b][h][w][c] bf16
//     block 640: pack w_def into MFMA A-fragment order (bf16) + zero stats
// A-frag layout: wtA[(((k*2+chalf)*4+og)*64+lane)*8+j]
//   = w_def[o = og*16+(lane&15)][c = chalf*32+(lane>>4)*8+j][k]
// ---------------------------------------------------------------------------
__global__ __launch_bounds__(256) void p0_prep(
        const float* __restrict__ x, const float* __restrict__ w_def,
        unsigned short* __restrict__ xbT, unsigned short* __restrict__ wtA,
        float* __restrict__ stats) {
    int t = threadIdx.x;
    int blk = blockIdx.x;
    if (blk == 640) {
        for (int u = 0; u < 144; ++u) {
            int idx = t + u * 256;                 // < 36864
            int k = idx >> 12;
            int r = idx & 4095;
            int chalf = r >> 11;
            int og = (r >> 9) & 3;
            int L = (r >> 3) & 63;
            int j = idx & 7;
            int o = og * 16 + (L & 15);
            int c = chalf * 32 + (L >> 4) * 8 + j;
            wtA[idx] = (unsigned short)f2bf_rne(w_def[(o * CIN + c) * 9 + k]);
        }
        if (t < 32) stats[t] = 0.f;
        return;
    }
    __shared__ unsigned short tile[WID * SROW];
    int b = blk / HEI, h = blk % HEI;
    const float* xp = x + (b * CIN) * HW + h * WID;
    for (int u = 0; u < 40; ++u) {
        int e = t + u * 256;                       // 0..10239
        int c = e / WID, w = e - c * WID;
        tile[w * SROW + c] = (unsigned short)f2bf_rne(xp[c * HW + w]);
    }
    __syncthreads();
    unsigned* dst = (unsigned*)(xbT + (b * HEI + h) * (WID * 64));
    for (int u = 0; u < 20; ++u) {
        int e = t + u * 256;                       // int units, 0..5119
        int w = e >> 5, cp = (e & 31) * 2;
        unsigned lo = tile[w * SROW + cp];
        unsigned hi = tile[w * SROW + cp + 1];
        dst[e] = lo | (hi << 16);
    }
}

// ---------------------------------------------------------------------------
// K1: offset conv (odd channels only) + fused BN statistics
// ---------------------------------------------------------------------------
__global__ __launch_bounds__(256) void k1_offconv(
        const float* __restrict__ x, const float* __restrict__ w_off,
        const float* __restrict__ b_off, float* __restrict__ off_odd,
        float* __restrict__ stats) {
    int t = threadIdx.x;
    int tid = blockIdx.x * 256 + t;
    int b = tid / HW, p = tid - b * HW;
    int h = p / WID;

    float acc[9];
#pragma unroll
    for (int j = 0; j < 9; ++j) acc[j] = b_off[2 * j + 1];

    const float* xb = x + b * CIN * HW + p;
    for (int c = 0; c < CIN; ++c) {
        const float* xc = xb + c * HW;
#pragma unroll
        for (int k = 0; k < 9; ++k) {
            int py = h + k - 4;
            float xv = (py >= 0 && py < HEI) ? xc[(k - 4) * WID] : 0.f;
#pragma unroll
            for (int j = 0; j < 9; ++j)
                acc[j] = fmaf(w_off[((2 * j + 1) * CIN + c) * 9 + k], xv, acc[j]);
        }
    }
#pragma unroll
    for (int j = 0; j < 9; ++j)
        off_odd[(b * 9 + j) * HW + p] = acc[j];

    // fused stats: block-reduce sum & sumsq per channel, one atomic each
    __shared__ float rs[4][9], rq[4][9];
    int lane = t & 63, wv = t >> 6;
#pragma unroll
    for (int j = 0; j < 9; ++j) {
        float v = acc[j], q = v * v;
#pragma unroll
        for (int o = 32; o > 0; o >>= 1) {
            v += __shfl_down(v, o);
            q += __shfl_down(q, o);
        }
        if (lane == 0) { rs[wv][j] = v; rq[wv][j] = q; }
    }
    __syncthreads();
    if (t < 18) {
        int j = t < 9 ? t : t - 9;
        float v = (t < 9) ? rs[0][j] + rs[1][j] + rs[2][j] + rs[3][j]
                          : rq[0][j] + rq[1][j] + rq[2][j] + rq[3][j];
        atomicAdd(&stats[t], v);
    }
}

// ---------------------------------------------------------------------------
// K3: normalize + tanh + _convert_offsets cumsums, in-place
// ---------------------------------------------------------------------------
__global__ __launch_bounds__(256) void k3_norm(
        float* __restrict__ off_odd, const float* __restrict__ stats,
        const float* __restrict__ gamma, const float* __restrict__ beta) {
    int tid = blockIdx.x * 256 + threadIdx.x;
    int b = tid / HW, p = tid - b * HW;

    float tv[9];
#pragma unroll
    for (int j = 0; j < 9; ++j) {
        float mean = stats[j] * (1.0f / NBN);
        float var  = stats[9 + j] * (1.0f / NBN) - mean * mean;
        float inv  = rsqrtf(var + 1e-5f);
        float v = off_odd[(b * 9 + j) * HW + p];
        tv[j] = tanhf((v - mean) * inv * gamma[2 * j + 1] + beta[2 * j + 1]);
    }
    float dx[9];
    dx[4] = tv[4];
#pragma unroll
    for (int i = 5; i < 9; ++i) dx[i] = dx[i - 1] + tv[i];
#pragma unroll
    for (int i = 3; i >= 0; --i) dx[i] = dx[i + 1] + tv[i];
#pragma unroll
    for (int j = 0; j < 9; ++j)
        off_odd[(b * 9 + j) * HW + p] = dx[j];
}

// ---------------------------------------------------------------------------
// K4: deformable conv via bf16 MFMA.
// Block = (b, row h): D[64 o][160 px] = sum_{k,c} Wt[o][kc] * S[kc][px]
// A (weights) in fragment regs, B (samples) built in-register from LDS x-row.
// Software-pipelined: prefetch next tap's row/dx/wfrags during compute.
// ---------------------------------------------------------------------------
__global__ __launch_bounds__(256, 3) void k4_deform_mfma(
        const unsigned short* __restrict__ xbT,
        const float* __restrict__ dxn,
        const unsigned short* __restrict__ wtA,
        const float* __restrict__ b_def,
        float* __restrict__ out) {
    __shared__ __align__(16) unsigned short xrow[WID * SROW];
    __shared__ float dxl[WID];

    int t = threadIdx.x;
    int blk = blockIdx.x;                    // 0..639
    int b = blk / HEI, h = blk - b * HEI;
    int wave = t >> 6, lane = t & 63;
    int l15 = lane & 15, q = lane >> 4;

    f32x4 acc[10];
#pragma unroll
    for (int i = 0; i < 10; ++i) acc[i] = (f32x4){0.f, 0.f, 0.f, 0.f};

    int klo = 4 - h; if (klo < 0) klo = 0;
    int khi = 163 - h; if (khi > 8) khi = 8;

    int4   pre[5];
    float  dpre = 0.f;
    bf16x8 wpre[2];

#define LOAD_STAGE(kk)                                                          \
    {                                                                           \
        int py = h + (kk) - 4;                                                  \
        const unsigned short* src = xbT + (b * HEI + py) * (WID * 64);          \
        _Pragma("unroll")                                                       \
        for (int u = 0; u < 5; ++u)                                             \
            pre[u] = *(const int4*)(src + (t + u * 256) * 8);                   \
        if (t < WID) dpre = dxn[(b * 9 + (kk)) * HW + h * WID + t];             \
        _Pragma("unroll")                                                       \
        for (int ch = 0; ch < 2; ++ch)                                          \
            wpre[ch] = *(const bf16x8*)(wtA + ((((kk) * 2 + ch) * 4 + wave) * 64 + lane) * 8); \
    }

    LOAD_STAGE(klo);

    for (int k = klo; k <= khi; ++k) {
        __syncthreads();                     // xrow free from previous readers
#pragma unroll
        for (int u = 0; u < 5; ++u) {
            int g = t + u * 256;
            int* dst = (int*)&xrow[(g >> 3) * SROW];
            int co = (g & 7) * 4;
            dst[co]     = pre[u].x;
            dst[co + 1] = pre[u].y;
            dst[co + 2] = pre[u].z;
            dst[co + 3] = pre[u].w;
        }
        if (t < WID) dxl[t] = dpre;
        bf16x8 wfc0 = wpre[0], wfc1 = wpre[1];
        if (k < khi) LOAD_STAGE(k + 1);      // prefetch overlaps compute below
        __syncthreads();

#pragma unroll
        for (int pxt = 0; pxt < 10; ++pxt) {
            int px = pxt * 16 + l15;
            float pxf = (float)px + dxl[px];
            float x0f = floorf(pxf);
            float fx = pxf - x0f;
            int x0 = (int)x0f;
            float s0 = (x0 >= 0 && x0 < WID) ? 1.f - fx : 0.f;
            float s1 = (x0 >= -1 && x0 < WID - 1) ? fx : 0.f;
            int xi0 = min(max(x0, 0), WID - 1);
            int xi1 = min(max(x0 + 1, 0), WID - 1);
            const int* r0 = (const int*)&xrow[xi0 * SROW];
            const int* r1 = (const int*)&xrow[xi1 * SROW];
#pragma unroll
            for (int ch = 0; ch < 2; ++ch) {
                int co = ch * 16 + q * 4;    // int index of this lane's c-octet
                U4 u;
#pragma unroll
                for (int ii = 0; ii < 4; ++ii) {
                    int A = r0[co + ii], B = r1[co + ii];
                    float alo = __int_as_float(A << 16);
                    float ahi = __int_as_float(A & 0xffff0000);
                    float blo = __int_as_float(B << 16);
                    float bhi = __int_as_float(B & 0xffff0000);
                    float slo = s0 * alo + s1 * blo;
                    float shi = s0 * ahi + s1 * bhi;
                    unsigned rl = __float_as_uint(slo) + 0x8000u;
                    unsigned rh = __float_as_uint(shi) + 0x8000u;
                    u.i[ii] = (int)__builtin_amdgcn_perm(rh, rl, 0x07060302u);
                }
                acc[pxt] = __builtin_amdgcn_mfma_f32_16x16x32_bf16(
                    ch ? wfc1 : wfc0, u.v, acc[pxt], 0, 0, 0);
            }
        }
    }

    // epilogue: D row = q*4+r (within o-tile), col = px = l15
    float bd[4];
#pragma unroll
    for (int r = 0; r < 4; ++r) bd[r] = b_def[wave * 16 + q * 4 + r];
#pragma unroll
    for (int pxt = 0; pxt < 10; ++pxt) {
#pragma unroll
        for (int r = 0; r < 4; ++r) {
            int o = wave * 16 + q * 4 + r;
            out[(b * COUT + o) * HW + h * WID + pxt * 16 + l15] = acc[pxt][r] + bd[r];
        }
    }
}

// ---------------------------------------------------------------------------
extern "C" void kernel_launch(void* const* d_in, const int* in_sizes, int n_in,
                              void* d_out, int out_size, void* d_ws, size_t ws_size,
                              hipStream_t stream) {
    const float* x     = (const float*)d_in[0];
    const float* w_off = (const float*)d_in[1];
    const float* b_off = (const float*)d_in[2];
    const float* gamma = (const float*)d_in[3];
    const float* beta  = (const float*)d_in[4];
    const float* w_def = (const float*)d_in[5];
    const float* b_def = (const float*)d_in[6];
    float* out = (float*)d_out;

    // workspace layout (16B-aligned pieces): ~16.9 MB total
    float* off_odd        = (float*)d_ws;                 // 921600 f
    float* stats          = off_odd + 921600;             // 32 f
    unsigned short* wtA   = (unsigned short*)(stats + 32);      // 36864 u16
    unsigned short* xbT   = wtA + 36864;                  // 6553600 u16 (offset 16B-aligned)

    p0_prep<<<641, 256, 0, stream>>>(x, w_def, xbT, wtA, stats);
    k1_offconv<<<400, 256, 0, stream>>>(x, w_off, b_off, off_odd, stats);
    k3_norm<<<400, 256, 0, stream>>>(off_odd, stats, gamma, beta);
    k4_deform_mfma<<<640, 256, 0, stream>>>(xbT, off_odd, wtA, b_def, out);
}

// Round 4
// 199.671 us; speedup vs baseline: 1.6089x; 1.1069x over previous
//
#include <hip/hip_runtime.h>
#include <math.h>

#define HW    25600
#define WID   160
#define HEI   160
#define BB    4
#define CIN   64
#define COUT  64
#define NBN   102400
#define SROW  66      // LDS row stride (bf16) for p0 transpose tile

typedef short  bf16x8 __attribute__((ext_vector_type(8)));
typedef float  f32x4  __attribute__((ext_vector_type(4)));

union U4 { int i[4]; bf16x8 v; };

__device__ __forceinline__ unsigned f2bf_rne(float f) {
    union { float f; unsigned u; } v; v.f = f;
    return (v.u + 0x7fffu + ((v.u >> 16) & 1u)) >> 16;
}

// ---------------------------------------------------------------------------
// P0: prep. blocks 0..639: transpose x[b][c][h][w] fp32 -> xbT[b][h][w][c] bf16
//     block 640: pack w_def into MFMA A-fragment order (bf16) + zero stats
// A-frag layout: wtA[(((k*2+chalf)*4+og)*64+lane)*8+j]
//   = w_def[o = og*16+(lane&15)][c = chalf*32+(lane>>4)*8+j][k]
// ---------------------------------------------------------------------------
__global__ __launch_bounds__(256) void p0_prep(
        const float* __restrict__ x, const float* __restrict__ w_def,
        unsigned short* __restrict__ xbT, unsigned short* __restrict__ wtA,
        float* __restrict__ stats) {
    int t = threadIdx.x;
    int blk = blockIdx.x;
    if (blk == 640) {
        for (int u = 0; u < 144; ++u) {
            int idx = t + u * 256;                 // < 36864
            int k = idx >> 12;
            int r = idx & 4095;
            int chalf = r >> 11;
            int og = (r >> 9) & 3;
            int L = (r >> 3) & 63;
            int j = idx & 7;
            int o = og * 16 + (L & 15);
            int c = chalf * 32 + (L >> 4) * 8 + j;
            wtA[idx] = (unsigned short)f2bf_rne(w_def[(o * CIN + c) * 9 + k]);
        }
        if (t < 32) stats[t] = 0.f;
        return;
    }
    __shared__ unsigned short tile[WID * SROW];
    int b = blk / HEI, h = blk % HEI;
    const float* xp = x + (b * CIN) * HW + h * WID;
    for (int u = 0; u < 40; ++u) {
        int e = t + u * 256;                       // 0..10239
        int c = e / WID, w = e - c * WID;
        tile[w * SROW + c] = (unsigned short)f2bf_rne(xp[c * HW + w]);
    }
    __syncthreads();
    unsigned* dst = (unsigned*)(xbT + (b * HEI + h) * (WID * 64));
    for (int u = 0; u < 20; ++u) {
        int e = t + u * 256;                       // int units, 0..5119
        int w = e >> 5, cp = (e & 31) * 2;
        unsigned lo = tile[w * SROW + cp];
        unsigned hi = tile[w * SROW + cp + 1];
        dst[e] = lo | (hi << 16);
    }
}

// ---------------------------------------------------------------------------
// K1: offset conv (odd channels only) + fused BN statistics
// ---------------------------------------------------------------------------
__global__ __launch_bounds__(256) void k1_offconv(
        const float* __restrict__ x, const float* __restrict__ w_off,
        const float* __restrict__ b_off, float* __restrict__ off_odd,
        float* __restrict__ stats) {
    int t = threadIdx.x;
    int tid = blockIdx.x * 256 + t;
    int b = tid / HW, p = tid - b * HW;
    int h = p / WID;

    float acc[9];
#pragma unroll
    for (int j = 0; j < 9; ++j) acc[j] = b_off[2 * j + 1];

    const float* xb = x + b * CIN * HW + p;
    for (int c = 0; c < CIN; ++c) {
        const float* xc = xb + c * HW;
#pragma unroll
        for (int k = 0; k < 9; ++k) {
            int py = h + k - 4;
            float xv = (py >= 0 && py < HEI) ? xc[(k - 4) * WID] : 0.f;
#pragma unroll
            for (int j = 0; j < 9; ++j)
                acc[j] = fmaf(w_off[((2 * j + 1) * CIN + c) * 9 + k], xv, acc[j]);
        }
    }
#pragma unroll
    for (int j = 0; j < 9; ++j)
        off_odd[(b * 9 + j) * HW + p] = acc[j];

    // fused stats: block-reduce sum & sumsq per channel, one atomic each
    __shared__ float rs[4][9], rq[4][9];
    int lane = t & 63, wv = t >> 6;
#pragma unroll
    for (int j = 0; j < 9; ++j) {
        float v = acc[j], q = v * v;
#pragma unroll
        for (int o = 32; o > 0; o >>= 1) {
            v += __shfl_down(v, o);
            q += __shfl_down(q, o);
        }
        if (lane == 0) { rs[wv][j] = v; rq[wv][j] = q; }
    }
    __syncthreads();
    if (t < 18) {
        int j = t < 9 ? t : t - 9;
        float v = (t < 9) ? rs[0][j] + rs[1][j] + rs[2][j] + rs[3][j]
                          : rq[0][j] + rq[1][j] + rq[2][j] + rq[3][j];
        atomicAdd(&stats[t], v);
    }
}

// ---------------------------------------------------------------------------
// K4 v3b: deformable conv via bf16 MFMA, fused BN-normalize+tanh+convert.
// Block = (b, h, half): 80 px x 64 outputs, all 9 taps.
//  prep : normalize+tanh+cumsum offsets for own 80 px; per-(k,px) sample
//         params (s0,s1,xi0,xi1) to LDS.
//  build: cooperatively build S[80 px][64 c] bf16 samples ONCE per tap,
//         reading xbT from global (32 lanes share a px -> coalesced),
//         written in B-fragment layout, stride 36 ints (bank-balanced b128).
//  mfma : each wave owns 16 outputs; 5 pxt x 2 ch fragment reads + MFMA.
// Fix vs R3: xi1 = clamp(x0+1) not clamp(x0)+1 (left-edge x0==-1 case).
// ---------------------------------------------------------------------------
__global__ __launch_bounds__(256, 5) void k4_deform_mfma(
        const unsigned short* __restrict__ xbT,
        const float* __restrict__ off_odd,
        const float* __restrict__ stats,
        const float* __restrict__ gamma,
        const float* __restrict__ beta,
        const unsigned short* __restrict__ wtA,
        const float* __restrict__ b_def,
        float* __restrict__ out) {
    __shared__ __align__(16) int S[80 * 36];       // samples, frag layout
    __shared__ float s0all[9][80], s1all[9][80];
    __shared__ int   xi0all[9][80], xi1all[9][80];

    int t   = threadIdx.x;
    int blk = blockIdx.x;                          // 0..1279
    int b    = blk / 320;
    int rem  = blk - b * 320;
    int h    = rem >> 1;
    int half = rem & 1;
    int p0   = half * 80;
    int wave = t >> 6, lane = t & 63;
    int l15 = lane & 15, q = lane >> 4;

    // ---- prep: offsets -> sampling params (fused k3) ----
    if (t < 80) {
        int px = p0 + t;
        float tv[9];
#pragma unroll
        for (int j = 0; j < 9; ++j) {
            float mean = stats[j] * (1.0f / NBN);
            float var  = stats[9 + j] * (1.0f / NBN) - mean * mean;
            float inv  = rsqrtf(var + 1e-5f);
            float v = off_odd[(b * 9 + j) * HW + h * WID + px];
            tv[j] = tanhf((v - mean) * inv * gamma[2 * j + 1] + beta[2 * j + 1]);
        }
        float dxv[9];
        dxv[4] = tv[4];
#pragma unroll
        for (int i = 5; i < 9; ++i) dxv[i] = dxv[i - 1] + tv[i];
#pragma unroll
        for (int i = 3; i >= 0; --i) dxv[i] = dxv[i + 1] + tv[i];
#pragma unroll
        for (int j = 0; j < 9; ++j) {
            float pxf = (float)px + dxv[j];
            float x0f = floorf(pxf);
            float fx  = pxf - x0f;
            int   x0  = (int)x0f;
            s0all[j][t] = (x0 >= 0 && x0 < WID) ? 1.f - fx : 0.f;
            s1all[j][t] = (x0 >= -1 && x0 < WID - 1) ? fx : 0.f;
            xi0all[j][t] = min(max(x0, 0), WID - 1);
            xi1all[j][t] = min(max(x0 + 1, 0), WID - 1);   // FIX: clamp x0+1, not xi0+1
        }
    }
    __syncthreads();

    f32x4 acc[5];
#pragma unroll
    for (int i = 0; i < 5; ++i) acc[i] = (f32x4){0.f, 0.f, 0.f, 0.f};

    int klo = 4 - h;   if (klo < 0) klo = 0;
    int khi = 163 - h; if (khi > 8) khi = 8;

    for (int k = klo; k <= khi; ++k) {
        int py = h + k - 4;
        const int* row = (const int*)xbT + (b * HEI + py) * (WID * 32);
        bf16x8 wf0 = *(const bf16x8*)(wtA + (((k * 2 + 0) * 4 + wave) * 64 + lane) * 8);
        bf16x8 wf1 = *(const bf16x8*)(wtA + (((k * 2 + 1) * 4 + wave) * 64 + lane) * 8);

        if (k != klo) __syncthreads();             // S free from prev consume
        // ---- build S once, cooperatively ----
#pragma unroll
        for (int u = 0; u < 10; ++u) {
            int idx = t + u * 256;                 // 0..2559
            int pxl = idx >> 5, ci = idx & 31;
            float sa = s0all[k][pxl], sb = s1all[k][pxl];
            int A  = row[xi0all[k][pxl] * 32 + ci];
            int Bv = row[xi1all[k][pxl] * 32 + ci];
            float alo = __int_as_float(A << 16);
            float ahi = __int_as_float(A & 0xffff0000);
            float blo = __int_as_float(Bv << 16);
            float bhi = __int_as_float(Bv & 0xffff0000);
            float slo = sa * alo + sb * blo;
            float shi = sa * ahi + sb * bhi;
            unsigned rl = __float_as_uint(slo) + 0x8000u;
            unsigned rh = __float_as_uint(shi) + 0x8000u;
            S[pxl * 36 + ci] = (int)__builtin_amdgcn_perm(rh, rl, 0x07060302u);
        }
        __syncthreads();                           // S visible

        // ---- consume: 5 pxt x 2 ch MFMAs per wave ----
#pragma unroll
        for (int pxt = 0; pxt < 5; ++pxt) {
            const int* sp = &S[(pxt * 16 + l15) * 36];
            U4 u0, u1;
            *(int4*)u0.i = *(const int4*)(sp + q * 4);
            *(int4*)u1.i = *(const int4*)(sp + 16 + q * 4);
            acc[pxt] = __builtin_amdgcn_mfma_f32_16x16x32_bf16(wf0, u0.v, acc[pxt], 0, 0, 0);
            acc[pxt] = __builtin_amdgcn_mfma_f32_16x16x32_bf16(wf1, u1.v, acc[pxt], 0, 0, 0);
        }
    }

    // ---- epilogue ----
    float bd[4];
#pragma unroll
    for (int r = 0; r < 4; ++r) bd[r] = b_def[wave * 16 + q * 4 + r];
#pragma unroll
    for (int pxt = 0; pxt < 5; ++pxt) {
#pragma unroll
        for (int r = 0; r < 4; ++r) {
            int o = wave * 16 + q * 4 + r;
            out[(b * COUT + o) * HW + h * WID + p0 + pxt * 16 + l15] = acc[pxt][r] + bd[r];
        }
    }
}

// ---------------------------------------------------------------------------
extern "C" void kernel_launch(void* const* d_in, const int* in_sizes, int n_in,
                              void* d_out, int out_size, void* d_ws, size_t ws_size,
                              hipStream_t stream) {
    const float* x     = (const float*)d_in[0];
    const float* w_off = (const float*)d_in[1];
    const float* b_off = (const float*)d_in[2];
    const float* gamma = (const float*)d_in[3];
    const float* beta  = (const float*)d_in[4];
    const float* w_def = (const float*)d_in[5];
    const float* b_def = (const float*)d_in[6];
    float* out = (float*)d_out;

    // workspace layout: ~16.9 MB
    float* off_odd      = (float*)d_ws;                    // 921600 f
    float* stats        = off_odd + 921600;                // 32 f
    unsigned short* wtA = (unsigned short*)(stats + 32);   // 36864 u16
    unsigned short* xbT = wtA + 36864;                     // 6553600 u16

    p0_prep<<<641, 256, 0, stream>>>(x, w_def, xbT, wtA, stats);
    k1_offconv<<<400, 256, 0, stream>>>(x, w_off, b_off, off_odd, stats);
    k4_deform_mfma<<<1280, 256, 0, stream>>>(xbT, off_odd, stats, gamma, beta,
                                             wtA, b_def, out);
}

// Round 5
// 163.542 us; speedup vs baseline: 1.9643x; 1.2209x over previous
//
#include <hip/hip_runtime.h>
#include <math.h>

#define HW    25600
#define WID   160
#define HEI   160
#define BB    4
#define CIN   64
#define COUT  64
#define NBN   102400
#define SROW  66      // LDS row stride (bf16) for p0 transpose tile

typedef short  bf16x8 __attribute__((ext_vector_type(8)));
typedef float  f32x4  __attribute__((ext_vector_type(4)));

union U4 { int i[4]; bf16x8 v; };

__device__ __forceinline__ unsigned f2bf_rne(float f) {
    union { float f; unsigned u; } v; v.f = f;
    return (v.u + 0x7fffu + ((v.u >> 16) & 1u)) >> 16;
}

// ---------------------------------------------------------------------------
// P0: prep. blocks 0..639: transpose x[b][c][h][w] fp32 -> xbT[b][h][w][c] bf16
//     block 640: pack w_def + w_off(odd) into MFMA A-fragment order + zero stats
// wtA [(((k*2+ch)*4+og)*64+lane)*8+j] = w_def[o=og*16+(lane&15)][c=ch*32+(lane>>4)*8+j][k]
// wofA[((k*2+ch)*64+lane)*8+jj]      = w_off[2*(lane&15)+1][c=ch*32+(lane>>4)*8+jj][k]
//                                      (rows lane&15 >= 9 zeroed)
// ---------------------------------------------------------------------------
__global__ __launch_bounds__(256) void p0_prep(
        const float* __restrict__ x, const float* __restrict__ w_def,
        const float* __restrict__ w_off,
        unsigned short* __restrict__ xbT, unsigned short* __restrict__ wtA,
        unsigned short* __restrict__ wofA, float* __restrict__ stats) {
    int t = threadIdx.x;
    int blk = blockIdx.x;
    if (blk == 640) {
        for (int u = 0; u < 144; ++u) {
            int idx = t + u * 256;                 // < 36864
            int k = idx >> 12;
            int r = idx & 4095;
            int chalf = r >> 11;
            int og = (r >> 9) & 3;
            int L = (r >> 3) & 63;
            int j = idx & 7;
            int o = og * 16 + (L & 15);
            int c = chalf * 32 + (L >> 4) * 8 + j;
            wtA[idx] = (unsigned short)f2bf_rne(w_def[(o * CIN + c) * 9 + k]);
        }
        for (int u = 0; u < 36; ++u) {
            int idx = t + u * 256;                 // < 9216
            int jj = idx & 7;
            int L  = (idx >> 3) & 63;
            int ch = (idx >> 9) & 1;
            int k  = idx >> 10;
            int j  = L & 15;
            int c  = ch * 32 + (L >> 4) * 8 + jj;
            wofA[idx] = (j < 9)
                ? (unsigned short)f2bf_rne(w_off[((2 * j + 1) * CIN + c) * 9 + k])
                : (unsigned short)0;
        }
        if (t < 32) stats[t] = 0.f;
        return;
    }
    __shared__ unsigned short tile[WID * SROW];
    int b = blk / HEI, h = blk % HEI;
    const float* xp = x + (b * CIN) * HW + h * WID;
    for (int u = 0; u < 40; ++u) {
        int e = t + u * 256;                       // 0..10239
        int c = e / WID, w = e - c * WID;
        tile[w * SROW + c] = (unsigned short)f2bf_rne(xp[c * HW + w]);
    }
    __syncthreads();
    unsigned* dst = (unsigned*)(xbT + (b * HEI + h) * (WID * 64));
    for (int u = 0; u < 20; ++u) {
        int e = t + u * 256;                       // int units, 0..5119
        int w = e >> 5, cp = (e & 31) * 2;
        unsigned lo = tile[w * SROW + cp];
        unsigned hi = tile[w * SROW + cp + 1];
        dst[e] = lo | (hi << 16);
    }
}

// ---------------------------------------------------------------------------
// K1 v2: offset conv via MFMA + fused bias + BN stats.
// Block = (b,h) XCD-swizzled: xcd=blk&7 owns h in [20*xcd, 20*xcd+20).
// B-fragments read DIRECTLY from xbT (global, L2-resident per XCD).
// Wave w owns px tiles {w, w+4, w+8} (waves 0,1: 3 tiles; 2,3: 2).
// D rows j=0..8 valid (A rows 9..15 zero-padded).
// ---------------------------------------------------------------------------
__global__ __launch_bounds__(256) void k1_offconv_mfma(
        const unsigned short* __restrict__ xbT,
        const unsigned short* __restrict__ wofA,
        const float* __restrict__ b_off,
        float* __restrict__ off_odd, float* __restrict__ stats) {
    int t = threadIdx.x;
    int blk = blockIdx.x;                          // 0..639
    int xcd = blk & 7;
    int idx = blk >> 3;                            // 0..79
    int b = idx / 20;
    int h = xcd * 20 + (idx - b * 20);
    int wave = t >> 6, lane = t & 63;
    int l15 = lane & 15, q = lane >> 4;

    int npx = (wave < 2) ? 3 : 2;
    f32x4 acc[3];
#pragma unroll
    for (int i = 0; i < 3; ++i) acc[i] = (f32x4){0.f, 0.f, 0.f, 0.f};

    int klo = 4 - h;   if (klo < 0) klo = 0;
    int khi = 163 - h; if (khi > 8) khi = 8;

    for (int k = klo; k <= khi; ++k) {
        int py = h + k - 4;
        const unsigned short* row = xbT + (b * HEI + py) * (WID * 64);
        bf16x8 a0 = *(const bf16x8*)(wofA + ((k * 2 + 0) * 64 + lane) * 8);
        bf16x8 a1 = *(const bf16x8*)(wofA + ((k * 2 + 1) * 64 + lane) * 8);
#pragma unroll
        for (int u = 0; u < 3; ++u) {
            if (u >= npx) break;
            int px = (wave + u * 4) * 16 + l15;
            const unsigned short* sp = row + px * 64;
            bf16x8 b0 = *(const bf16x8*)(sp + q * 8);
            bf16x8 b1 = *(const bf16x8*)(sp + 32 + q * 8);
            acc[u] = __builtin_amdgcn_mfma_f32_16x16x32_bf16(a0, b0, acc[u], 0, 0, 0);
            acc[u] = __builtin_amdgcn_mfma_f32_16x16x32_bf16(a1, b1, acc[u], 0, 0, 0);
        }
    }

    // epilogue: bias, store, fused BN stats
    float sS[4] = {0.f, 0.f, 0.f, 0.f}, sQ[4] = {0.f, 0.f, 0.f, 0.f};
#pragma unroll
    for (int u = 0; u < 3; ++u) {
        if (u >= npx) break;
        int px = (wave + u * 4) * 16 + l15;
#pragma unroll
        for (int r = 0; r < 4; ++r) {
            int j = q * 4 + r;
            if (j < 9) {
                float v = acc[u][r] + b_off[2 * j + 1];
                off_odd[(b * 9 + j) * HW + h * WID + px] = v;
                sS[r] += v; sQ[r] += v * v;
            }
        }
    }
#pragma unroll
    for (int o = 1; o < 16; o <<= 1) {
#pragma unroll
        for (int r = 0; r < 4; ++r) {
            sS[r] += __shfl_xor(sS[r], o);
            sQ[r] += __shfl_xor(sQ[r], o);
        }
    }
    __shared__ float redS[4][16], redQ[4][16];
    if (l15 == 0) {
#pragma unroll
        for (int r = 0; r < 4; ++r) {
            int j = q * 4 + r;
            if (j < 9) { redS[wave][j] = sS[r]; redQ[wave][j] = sQ[r]; }
        }
    }
    __syncthreads();
    if (t < 18) {
        int j = (t < 9) ? t : t - 9;
        float v = (t < 9) ? redS[0][j] + redS[1][j] + redS[2][j] + redS[3][j]
                          : redQ[0][j] + redQ[1][j] + redQ[2][j] + redQ[3][j];
        atomicAdd(&stats[t], v);
    }
}

// ---------------------------------------------------------------------------
// K4: deformable conv via bf16 MFMA, fused BN-normalize+tanh+convert.
// Block = (b, h, half) XCD-swizzled; 80 px x 64 outputs, all 9 taps.
// ---------------------------------------------------------------------------
__global__ __launch_bounds__(256, 5) void k4_deform_mfma(
        const unsigned short* __restrict__ xbT,
        const float* __restrict__ off_odd,
        const float* __restrict__ stats,
        const float* __restrict__ gamma,
        const float* __restrict__ beta,
        const unsigned short* __restrict__ wtA,
        const float* __restrict__ b_def,
        float* __restrict__ out) {
    __shared__ __align__(16) int S[80 * 36];       // samples, frag layout
    __shared__ float s0all[9][80], s1all[9][80];
    __shared__ int   xi0all[9][80], xi1all[9][80];

    int t   = threadIdx.x;
    int blk = blockIdx.x;                          // 0..1279
    int xcd = blk & 7;
    int idx = blk >> 3;                            // 0..159
    int b   = idx / 40;
    int r2  = idx - b * 40;                        // 0..39
    int h   = xcd * 20 + (r2 >> 1);
    int half = r2 & 1;
    int p0  = half * 80;
    int wave = t >> 6, lane = t & 63;
    int l15 = lane & 15, q = lane >> 4;

    // ---- prep: offsets -> sampling params (fused BN+tanh+convert) ----
    if (t < 80) {
        int px = p0 + t;
        float tv[9];
#pragma unroll
        for (int j = 0; j < 9; ++j) {
            float mean = stats[j] * (1.0f / NBN);
            float var  = stats[9 + j] * (1.0f / NBN) - mean * mean;
            float inv  = rsqrtf(var + 1e-5f);
            float v = off_odd[(b * 9 + j) * HW + h * WID + px];
            tv[j] = tanhf((v - mean) * inv * gamma[2 * j + 1] + beta[2 * j + 1]);
        }
        float dxv[9];
        dxv[4] = tv[4];
#pragma unroll
        for (int i = 5; i < 9; ++i) dxv[i] = dxv[i - 1] + tv[i];
#pragma unroll
        for (int i = 3; i >= 0; --i) dxv[i] = dxv[i + 1] + tv[i];
#pragma unroll
        for (int j = 0; j < 9; ++j) {
            float pxf = (float)px + dxv[j];
            float x0f = floorf(pxf);
            float fx  = pxf - x0f;
            int   x0  = (int)x0f;
            s0all[j][t] = (x0 >= 0 && x0 < WID) ? 1.f - fx : 0.f;
            s1all[j][t] = (x0 >= -1 && x0 < WID - 1) ? fx : 0.f;
            xi0all[j][t] = min(max(x0, 0), WID - 1);
            xi1all[j][t] = min(max(x0 + 1, 0), WID - 1);
        }
    }
    __syncthreads();

    f32x4 acc[5];
#pragma unroll
    for (int i = 0; i < 5; ++i) acc[i] = (f32x4){0.f, 0.f, 0.f, 0.f};

    int klo = 4 - h;   if (klo < 0) klo = 0;
    int khi = 163 - h; if (khi > 8) khi = 8;

    for (int k = klo; k <= khi; ++k) {
        int py = h + k - 4;
        const int* row = (const int*)xbT + (b * HEI + py) * (WID * 32);
        bf16x8 wf0 = *(const bf16x8*)(wtA + (((k * 2 + 0) * 4 + wave) * 64 + lane) * 8);
        bf16x8 wf1 = *(const bf16x8*)(wtA + (((k * 2 + 1) * 4 + wave) * 64 + lane) * 8);

        if (k != klo) __syncthreads();             // S free from prev consume
        // ---- build S once, cooperatively ----
#pragma unroll
        for (int u = 0; u < 10; ++u) {
            int idx2 = t + u * 256;                // 0..2559
            int pxl = idx2 >> 5, ci = idx2 & 31;
            float sa = s0all[k][pxl], sb = s1all[k][pxl];
            int A  = row[xi0all[k][pxl] * 32 + ci];
            int Bv = row[xi1all[k][pxl] * 32 + ci];
            float alo = __int_as_float(A << 16);
            float ahi = __int_as_float(A & 0xffff0000);
            float blo = __int_as_float(Bv << 16);
            float bhi = __int_as_float(Bv & 0xffff0000);
            float slo = sa * alo + sb * blo;
            float shi = sa * ahi + sb * bhi;
            unsigned rl = __float_as_uint(slo) + 0x8000u;
            unsigned rh = __float_as_uint(shi) + 0x8000u;
            S[pxl * 36 + ci] = (int)__builtin_amdgcn_perm(rh, rl, 0x07060302u);
        }
        __syncthreads();                           // S visible

        // ---- consume: 5 pxt x 2 ch MFMAs per wave ----
#pragma unroll
        for (int pxt = 0; pxt < 5; ++pxt) {
            const int* sp = &S[(pxt * 16 + l15) * 36];
            U4 u0, u1;
            *(int4*)u0.i = *(const int4*)(sp + q * 4);
            *(int4*)u1.i = *(const int4*)(sp + 16 + q * 4);
            acc[pxt] = __builtin_amdgcn_mfma_f32_16x16x32_bf16(wf0, u0.v, acc[pxt], 0, 0, 0);
            acc[pxt] = __builtin_amdgcn_mfma_f32_16x16x32_bf16(wf1, u1.v, acc[pxt], 0, 0, 0);
        }
    }

    // ---- epilogue ----
    float bd[4];
#pragma unroll
    for (int r = 0; r < 4; ++r) bd[r] = b_def[wave * 16 + q * 4 + r];
#pragma unroll
    for (int pxt = 0; pxt < 5; ++pxt) {
#pragma unroll
        for (int r = 0; r < 4; ++r) {
            int o = wave * 16 + q * 4 + r;
            out[(b * COUT + o) * HW + h * WID + p0 + pxt * 16 + l15] = acc[pxt][r] + bd[r];
        }
    }
}

// ---------------------------------------------------------------------------
extern "C" void kernel_launch(void* const* d_in, const int* in_sizes, int n_in,
                              void* d_out, int out_size, void* d_ws, size_t ws_size,
                              hipStream_t stream) {
    const float* x     = (const float*)d_in[0];
    const float* w_off = (const float*)d_in[1];
    const float* b_off = (const float*)d_in[2];
    const float* gamma = (const float*)d_in[3];
    const float* beta  = (const float*)d_in[4];
    const float* w_def = (const float*)d_in[5];
    const float* b_def = (const float*)d_in[6];
    float* out = (float*)d_out;

    // workspace layout: ~17.0 MB
    float* off_odd       = (float*)d_ws;                    // 921600 f
    float* stats         = off_odd + 921600;                // 32 f
    unsigned short* wtA  = (unsigned short*)(stats + 32);   // 36864 u16
    unsigned short* wofA = wtA + 36864;                     // 9216 u16
    unsigned short* xbT  = wofA + 9216;                     // 6553600 u16

    p0_prep<<<641, 256, 0, stream>>>(x, w_def, w_off, xbT, wtA, wofA, stats);
    k1_offconv_mfma<<<640, 256, 0, stream>>>(xbT, wofA, b_off, off_odd, stats);
    k4_deform_mfma<<<1280, 256, 0, stream>>>(xbT, off_odd, stats, gamma, beta,
                                             wtA, b_def, out);
}

// Round 6
// 154.789 us; speedup vs baseline: 2.0753x; 1.0565x over previous
//
#include <hip/hip_runtime.h>
#include <math.h>

#define HW    25600
#define WID   160
#define HEI   160
#define BB    4
#define CIN   64
#define COUT  64
#define NBN   102400
#define TSTR  162     // p0 LDS tile stride in shorts: int-stride 81 == 17 mod 32

typedef short  bf16x8 __attribute__((ext_vector_type(8)));
typedef float  f32x4  __attribute__((ext_vector_type(4)));

union U4 { int i[4]; bf16x8 v; };

__device__ __forceinline__ unsigned f2bf_rne(float f) {
    union { float f; unsigned u; } v; v.f = f;
    return (v.u + 0x7fffu + ((v.u >> 16) & 1u)) >> 16;
}

// ---------------------------------------------------------------------------
// P0: prep. blocks 0..639: transpose x[b][c][h][w] fp32 -> xbT[b][h][w][c] bf16
//     (float4 reads, LDS [c][w] stride-162 tile, paired-int phases)
//     block 640: pack w_def + w_off(odd) into MFMA A-fragment order + zero stats
// ---------------------------------------------------------------------------
__global__ __launch_bounds__(256) void p0_prep(
        const float* __restrict__ x, const float* __restrict__ w_def,
        const float* __restrict__ w_off,
        unsigned short* __restrict__ xbT, unsigned short* __restrict__ wtA,
        unsigned short* __restrict__ wofA, float* __restrict__ stats) {
    int t = threadIdx.x;
    int blk = blockIdx.x;
    if (blk == 640) {
        for (int u = 0; u < 144; ++u) {
            int idx = t + u * 256;                 // < 36864
            int k = idx >> 12;
            int r = idx & 4095;
            int chalf = r >> 11;
            int og = (r >> 9) & 3;
            int L = (r >> 3) & 63;
            int j = idx & 7;
            int o = og * 16 + (L & 15);
            int c = chalf * 32 + (L >> 4) * 8 + j;
            wtA[idx] = (unsigned short)f2bf_rne(w_def[(o * CIN + c) * 9 + k]);
        }
        for (int u = 0; u < 36; ++u) {
            int idx = t + u * 256;                 // < 9216
            int jj = idx & 7;
            int L  = (idx >> 3) & 63;
            int ch = (idx >> 9) & 1;
            int k  = idx >> 10;
            int j  = L & 15;
            int c  = ch * 32 + (L >> 4) * 8 + jj;
            wofA[idx] = (j < 9)
                ? (unsigned short)f2bf_rne(w_off[((2 * j + 1) * CIN + c) * 9 + k])
                : (unsigned short)0;
        }
        if (t < 32) stats[t] = 0.f;
        return;
    }
    __shared__ __align__(16) unsigned short tile[CIN * TSTR];  // [c][w]
    int b = blk / HEI, h = blk % HEI;
    const float* xp = x + (b * CIN) * HW + h * WID;
    unsigned* ti = (unsigned*)tile;
#pragma unroll
    for (int u = 0; u < 10; ++u) {
        int e = t + u * 256;                       // 0..2559 = 64 c x 40 quads
        int c = e / 40, wq = e - c * 40;
        const float4 v = *(const float4*)(xp + c * HW + 4 * wq);
        unsigned p01 = f2bf_rne(v.x) | (f2bf_rne(v.y) << 16);
        unsigned p23 = f2bf_rne(v.z) | (f2bf_rne(v.w) << 16);
        ti[81 * c + 2 * wq]     = p01;
        ti[81 * c + 2 * wq + 1] = p23;
    }
    __syncthreads();
    unsigned* dst = (unsigned*)(xbT + (b * HEI + h) * (WID * 64));
#pragma unroll
    for (int u = 0; u < 20; ++u) {
        int e = t + u * 256;                       // 0..5119 = 160 w x 32 cpair
        int w = e >> 5, cp = e & 31;
        unsigned lo = tile[(2 * cp) * TSTR + w];
        unsigned hi = tile[(2 * cp + 1) * TSTR + w];
        dst[e] = lo | (hi << 16);
    }
}

// ---------------------------------------------------------------------------
// K1: offset conv via MFMA + fused bias + BN stats (unchanged from R5).
// ---------------------------------------------------------------------------
__global__ __launch_bounds__(256) void k1_offconv_mfma(
        const unsigned short* __restrict__ xbT,
        const unsigned short* __restrict__ wofA,
        const float* __restrict__ b_off,
        float* __restrict__ off_odd, float* __restrict__ stats) {
    int t = threadIdx.x;
    int blk = blockIdx.x;                          // 0..639
    int xcd = blk & 7;
    int idx = blk >> 3;                            // 0..79
    int b = idx / 20;
    int h = xcd * 20 + (idx - b * 20);
    int wave = t >> 6, lane = t & 63;
    int l15 = lane & 15, q = lane >> 4;

    int npx = (wave < 2) ? 3 : 2;
    f32x4 acc[3];
#pragma unroll
    for (int i = 0; i < 3; ++i) acc[i] = (f32x4){0.f, 0.f, 0.f, 0.f};

    int klo = 4 - h;   if (klo < 0) klo = 0;
    int khi = 163 - h; if (khi > 8) khi = 8;

    for (int k = klo; k <= khi; ++k) {
        int py = h + k - 4;
        const unsigned short* row = xbT + (b * HEI + py) * (WID * 64);
        bf16x8 a0 = *(const bf16x8*)(wofA + ((k * 2 + 0) * 64 + lane) * 8);
        bf16x8 a1 = *(const bf16x8*)(wofA + ((k * 2 + 1) * 64 + lane) * 8);
#pragma unroll
        for (int u = 0; u < 3; ++u) {
            if (u >= npx) break;
            int px = (wave + u * 4) * 16 + l15;
            const unsigned short* sp = row + px * 64;
            bf16x8 b0 = *(const bf16x8*)(sp + q * 8);
            bf16x8 b1 = *(const bf16x8*)(sp + 32 + q * 8);
            acc[u] = __builtin_amdgcn_mfma_f32_16x16x32_bf16(a0, b0, acc[u], 0, 0, 0);
            acc[u] = __builtin_amdgcn_mfma_f32_16x16x32_bf16(a1, b1, acc[u], 0, 0, 0);
        }
    }

    float sS[4] = {0.f, 0.f, 0.f, 0.f}, sQ[4] = {0.f, 0.f, 0.f, 0.f};
#pragma unroll
    for (int u = 0; u < 3; ++u) {
        if (u >= npx) break;
        int px = (wave + u * 4) * 16 + l15;
#pragma unroll
        for (int r = 0; r < 4; ++r) {
            int j = q * 4 + r;
            if (j < 9) {
                float v = acc[u][r] + b_off[2 * j + 1];
                off_odd[(b * 9 + j) * HW + h * WID + px] = v;
                sS[r] += v; sQ[r] += v * v;
            }
        }
    }
#pragma unroll
    for (int o = 1; o < 16; o <<= 1) {
#pragma unroll
        for (int r = 0; r < 4; ++r) {
            sS[r] += __shfl_xor(sS[r], o);
            sQ[r] += __shfl_xor(sQ[r], o);
        }
    }
    __shared__ float redS[4][16], redQ[4][16];
    if (l15 == 0) {
#pragma unroll
        for (int r = 0; r < 4; ++r) {
            int j = q * 4 + r;
            if (j < 9) { redS[wave][j] = sS[r]; redQ[wave][j] = sQ[r]; }
        }
    }
    __syncthreads();
    if (t < 18) {
        int j = (t < 9) ? t : t - 9;
        float v = (t < 9) ? redS[0][j] + redS[1][j] + redS[2][j] + redS[3][j]
                          : redQ[0][j] + redQ[1][j] + redQ[2][j] + redQ[3][j];
        atomicAdd(&stats[t], v);
    }
}

// ---------------------------------------------------------------------------
// K4 v4: deformable conv via bf16 MFMA.
//  - batched register prefetch of next tap's 20 sample ints + weight frags,
//    issued during current tap's consume (hides L2 latency behind MFMA)
//  - double-buffered S -> ONE barrier per tap
//  - packed sampling params (s0,s1, xi0|xi1<<16) in LDS
// ---------------------------------------------------------------------------
__global__ __launch_bounds__(256, 5) void k4_deform_mfma(
        const unsigned short* __restrict__ xbT,
        const float* __restrict__ off_odd,
        const float* __restrict__ stats,
        const float* __restrict__ gamma,
        const float* __restrict__ beta,
        const unsigned short* __restrict__ wtA,
        const float* __restrict__ b_def,
        float* __restrict__ out) {
    __shared__ __align__(16) int S[2][80 * 36];    // samples, frag layout, dbuf
    __shared__ float P0[9][80], P1[9][80];
    __shared__ int   PXI[9][80];                   // xi0 | xi1<<16

    int t   = threadIdx.x;
    int blk = blockIdx.x;                          // 0..1279
    int xcd = blk & 7;
    int idx = blk >> 3;                            // 0..159
    int b   = idx / 40;
    int r2  = idx - b * 40;                        // 0..39
    int h   = xcd * 20 + (r2 >> 1);
    int half = r2 & 1;
    int p0  = half * 80;
    int wave = t >> 6, lane = t & 63;
    int l15 = lane & 15, q = lane >> 4;

    // ---- prep: offsets -> sampling params (fused BN+tanh+convert) ----
    if (t < 80) {
        int px = p0 + t;
        float tv[9];
#pragma unroll
        for (int j = 0; j < 9; ++j) {
            float mean = stats[j] * (1.0f / NBN);
            float var  = stats[9 + j] * (1.0f / NBN) - mean * mean;
            float inv  = rsqrtf(var + 1e-5f);
            float v = off_odd[(b * 9 + j) * HW + h * WID + px];
            tv[j] = tanhf((v - mean) * inv * gamma[2 * j + 1] + beta[2 * j + 1]);
        }
        float dxv[9];
        dxv[4] = tv[4];
#pragma unroll
        for (int i = 5; i < 9; ++i) dxv[i] = dxv[i - 1] + tv[i];
#pragma unroll
        for (int i = 3; i >= 0; --i) dxv[i] = dxv[i + 1] + tv[i];
#pragma unroll
        for (int j = 0; j < 9; ++j) {
            float pxf = (float)px + dxv[j];
            float x0f = floorf(pxf);
            float fx  = pxf - x0f;
            int   x0  = (int)x0f;
            P0[j][t] = (x0 >= 0 && x0 < WID) ? 1.f - fx : 0.f;
            P1[j][t] = (x0 >= -1 && x0 < WID - 1) ? fx : 0.f;
            int xi0 = min(max(x0, 0), WID - 1);
            int xi1 = min(max(x0 + 1, 0), WID - 1);
            PXI[j][t] = xi0 | (xi1 << 16);
        }
    }
    __syncthreads();

    f32x4 acc[5];
#pragma unroll
    for (int i = 0; i < 5; ++i) acc[i] = (f32x4){0.f, 0.f, 0.f, 0.f};

    int klo = 4 - h;   if (klo < 0) klo = 0;
    int khi = 163 - h; if (khi > 8) khi = 8;

    int    A[10], Bv[10];
    bf16x8 wpa, wpb;
    int    pxb = t >> 5, ci = t & 31;

#define PF(kk)                                                                  \
    {                                                                           \
        int py = h + (kk) - 4;                                                  \
        const int* row = (const int*)xbT + (b * HEI + py) * (WID * 32);         \
        _Pragma("unroll")                                                       \
        for (int u = 0; u < 10; ++u) {                                          \
            int xi = PXI[kk][pxb + u * 8];                                      \
            A[u]  = row[(xi & 0xffff) * 32 + ci];                               \
            Bv[u] = row[(xi >> 16) * 32 + ci];                                  \
        }                                                                       \
        wpa = *(const bf16x8*)(wtA + ((((kk) * 2 + 0) * 4 + wave) * 64 + lane) * 8); \
        wpb = *(const bf16x8*)(wtA + ((((kk) * 2 + 1) * 4 + wave) * 64 + lane) * 8); \
    }

    PF(klo);
    int buf = 0;

    for (int k = klo; k <= khi; ++k) {
        int* Sb = S[buf];
        // ---- build S[buf] from prefetched registers (pure VALU) ----
#pragma unroll
        for (int u = 0; u < 10; ++u) {
            int pxl = pxb + u * 8;
            float sa = P0[k][pxl], sb = P1[k][pxl];
            int Aa = A[u], Bb = Bv[u];
            float alo = __int_as_float(Aa << 16);
            float ahi = __int_as_float(Aa & 0xffff0000);
            float blo = __int_as_float(Bb << 16);
            float bhi = __int_as_float(Bb & 0xffff0000);
            float slo = sa * alo + sb * blo;
            float shi = sa * ahi + sb * bhi;
            unsigned rl = __float_as_uint(slo) + 0x8000u;
            unsigned rh = __float_as_uint(shi) + 0x8000u;
            Sb[pxl * 36 + ci] = (int)__builtin_amdgcn_perm(rh, rl, 0x07060302u);
        }
        __syncthreads();                           // S[buf] ready (1 barrier/tap)

        bf16x8 wf0 = wpa, wf1 = wpb;
        if (k < khi) PF(k + 1);                    // prefetch overlaps consume

        // ---- consume: 5 pxt x 2 ch MFMAs per wave ----
#pragma unroll
        for (int pxt = 0; pxt < 5; ++pxt) {
            const int* sp = &Sb[(pxt * 16 + l15) * 36];
            U4 u0, u1;
            *(int4*)u0.i = *(const int4*)(sp + q * 4);
            *(int4*)u1.i = *(const int4*)(sp + 16 + q * 4);
            acc[pxt] = __builtin_amdgcn_mfma_f32_16x16x32_bf16(wf0, u0.v, acc[pxt], 0, 0, 0);
            acc[pxt] = __builtin_amdgcn_mfma_f32_16x16x32_bf16(wf1, u1.v, acc[pxt], 0, 0, 0);
        }
        buf ^= 1;
    }
#undef PF

    // ---- epilogue ----
    float bd[4];
#pragma unroll
    for (int r = 0; r < 4; ++r) bd[r] = b_def[wave * 16 + q * 4 + r];
#pragma unroll
    for (int pxt = 0; pxt < 5; ++pxt) {
#pragma unroll
        for (int r = 0; r < 4; ++r) {
            int o = wave * 16 + q * 4 + r;
            out[(b * COUT + o) * HW + h * WID + p0 + pxt * 16 + l15] = acc[pxt][r] + bd[r];
        }
    }
}

// ---------------------------------------------------------------------------
extern "C" void kernel_launch(void* const* d_in, const int* in_sizes, int n_in,
                              void* d_out, int out_size, void* d_ws, size_t ws_size,
                              hipStream_t stream) {
    const float* x     = (const float*)d_in[0];
    const float* w_off = (const float*)d_in[1];
    const float* b_off = (const float*)d_in[2];
    const float* gamma = (const float*)d_in[3];
    const float* beta  = (const float*)d_in[4];
    const float* w_def = (const float*)d_in[5];
    const float* b_def = (const float*)d_in[6];
    float* out = (float*)d_out;

    // workspace layout: ~17.0 MB
    float* off_odd       = (float*)d_ws;                    // 921600 f
    float* stats         = off_odd + 921600;                // 32 f
    unsigned short* wtA  = (unsigned short*)(stats + 32);   // 36864 u16
    unsigned short* wofA = wtA + 36864;                     // 9216 u16
    unsigned short* xbT  = wofA + 9216;                     // 6553600 u16

    p0_prep<<<641, 256, 0, stream>>>(x, w_def, w_off, xbT, wtA, wofA, stats);
    k1_offconv_mfma<<<640, 256, 0, stream>>>(xbT, wofA, b_off, off_odd, stats);
    k4_deform_mfma<<<1280, 256, 0, stream>>>(xbT, off_odd, stats, gamma, beta,
                                             wtA, b_def, out);
}